// Round 11
// baseline (638.132 us; speedup 1.0000x reference)
//
#include <hip/hip_runtime.h>

#define Bn   64
#define Tn   128
#define NKn  200
#define En   64
#define Ln   40

__device__ __forceinline__ float sigm_f(float x){ return 1.0f/(1.0f+__expf(-x)); }
__device__ __forceinline__ float tanh_f(float x){ float e=__expf(2.0f*x); return 1.0f-2.0f/(e+1.0f); }
__device__ __forceinline__ float rdl(float v, int ln){
  return __uint_as_float(__builtin_amdgcn_readlane(__float_as_uint(v), (unsigned)ln));
}

// ---------------- both embedding gather-sums in one grid ----------------
__global__ __launch_bounds__(256) void embed_all(const int* __restrict__ sup,
                                                 const int* __restrict__ tgt,
                                                 const float* __restrict__ emb,
                                                 float* __restrict__ sup_enc,
                                                 float* __restrict__ tgt_enc){
  int tid = threadIdx.x;
  int gr  = blockIdx.x*16 + (tid>>4);
  int e4  = tid & 15;
  const int* tr; float* out;
  if (gr < 12800){ tr = sup + (size_t)gr*Ln;        out = sup_enc + (size_t)gr*64; }
  else           { int r2=gr-12800; tr = tgt + (size_t)r2*Ln; out = tgt_enc + (size_t)r2*64; }
  float4 acc = {0.f,0.f,0.f,0.f};
  #pragma unroll 4
  for (int t=0;t<Ln;t++){
    int tok = tr[t];
    float4 v = ((const float4*)emb)[(size_t)tok*16 + e4];
    acc.x+=v.x; acc.y+=v.y; acc.z+=v.z; acc.w+=v.w;
  }
  ((float4*)out)[e4] = acc;
}

// ------- both support GEMMs in ONE pass: thread holds Wa row g AND Wb row g --------
__global__ __launch_bounds__(256,1) void gemm_sup2(const float* __restrict__ x,
                                                   const float* __restrict__ Wa, const float* __restrict__ Wb,
                                                   const float* __restrict__ ba1,const float* __restrict__ ba2,
                                                   const float* __restrict__ bb1,const float* __restrict__ bb2,
                                                   float* __restrict__ outa, float* __restrict__ outb){
  int tid=threadIdx.x, l=tid&63, w=tid>>6;
  int g=tid;
  int m0 = blockIdx.x*16;
  __shared__ __attribute__((aligned(16))) float xs[16*64];
  #pragma unroll
  for(int q=0;q<4;q++){ int r=4*w+q; xs[r*64+l]=x[(size_t)(m0+r)*64+l]; }
  float wa[64], wb[64];
  {
    const float4* A4=(const float4*)(Wa + (size_t)g*64);
    const float4* B4=(const float4*)(Wb + (size_t)g*64);
    #pragma unroll
    for(int q=0;q<16;q++){
      float4 va=A4[q]; wa[4*q]=va.x; wa[4*q+1]=va.y; wa[4*q+2]=va.z; wa[4*q+3]=va.w;
      float4 vb=B4[q]; wb[4*q]=vb.x; wb[4*q+1]=vb.y; wb[4*q+2]=vb.z; wb[4*q+3]=vb.w;
    }
  }
  float biasa=ba1[g]+ba2[g], biasb=bb1[g]+bb2[g];
  __syncthreads();
  #pragma unroll
  for(int r=0;r<16;r++){
    const float4* x4=(const float4*)&xs[r*64];
    float a0=biasa,a1=0.f,b0=biasb,b1=0.f;
    #pragma unroll
    for(int kc=0;kc<16;kc++){
      float4 h4=x4[kc];
      a0=fmaf(wa[4*kc+0],h4.x,a0); b0=fmaf(wb[4*kc+0],h4.x,b0);
      a1=fmaf(wa[4*kc+1],h4.y,a1); b1=fmaf(wb[4*kc+1],h4.y,b1);
      a0=fmaf(wa[4*kc+2],h4.z,a0); b0=fmaf(wb[4*kc+2],h4.z,b0);
      a1=fmaf(wa[4*kc+3],h4.w,a1); b1=fmaf(wb[4*kc+3],h4.w,b1);
    }
    outa[(size_t)(m0+r)*256+g]=a0+a1;
    outb[(size_t)(m0+r)*256+g]=b0+b1;
  }
}

// ---------------- BiLSTM: R2-exact structure (best measured: 113 us) ----------------
__global__ __launch_bounds__(256,1) void lstm_seq(const float* __restrict__ xg_f,
                                                  const float* __restrict__ xg_b,
                                                  const float* __restrict__ Whh_f,
                                                  const float* __restrict__ Whh_b,
                                                  float* __restrict__ hf,
                                                  float* __restrict__ hb){
  int tid=threadIdx.x, l=tid&63, w=tid>>6;
  int dir=blockIdx.x>>6, b=blockIdx.x&63;
  const float* xg = dir? xg_b : xg_f;
  const float* Whh= dir? Whh_b: Whh_f;
  float* out = dir? hb : hf;
  float wr[64];
  const float4* W4=(const float4*)(Whh+(size_t)(w*64+l)*64);
  #pragma unroll
  for(int q=0;q<16;q++){ float4 v=W4[q]; wr[4*q]=v.x; wr[4*q+1]=v.y; wr[4*q+2]=v.z; wr[4*q+3]=v.w; }
  __shared__ float z_s[2][256];
  float h=0.f, c=0.f;
  const int tstart = dir?(NKn-1):0, dt = dir?-1:1;
  const float* xgb = xg + (size_t)b*NKn*256 + w*64 + l;
  float xv = xgb[(size_t)tstart*256];
  for(int s=0;s<NKn;s++){
    int t=tstart+s*dt;
    float xnx=0.f;
    if (s<NKn-1) xnx = xgb[(size_t)(t+dt)*256];     // prefetch next step's xg
    float a0=xv,a1=0.f,a2=0.f,a3=0.f;
    #pragma unroll
    for(int q=0;q<16;q++){
      a0=fmaf(wr[4*q+0],rdl(h,4*q+0),a0);
      a1=fmaf(wr[4*q+1],rdl(h,4*q+1),a1);
      a2=fmaf(wr[4*q+2],rdl(h,4*q+2),a2);
      a3=fmaf(wr[4*q+3],rdl(h,4*q+3),a3);
    }
    z_s[s&1][tid]=(a0+a1)+(a2+a3);
    __syncthreads();                                 // double-buffered z -> only barrier
    float zi=z_s[s&1][l], zf=z_s[s&1][64+l], zg=z_s[s&1][128+l], zo=z_s[s&1][192+l];
    c = sigm_f(zf)*c + sigm_f(zi)*tanh_f(zg);        // redundant per wave, h stays in regs
    h = sigm_f(zo)*tanh_f(c);
    if(w==0) out[((size_t)b*NKn+t)*64+l]=h;
    xv=xnx;
  }
}

// ---------------- sup_emb = hf + hb + sup_enc; sn = ||sup_emb|| (800 blocks) ----------------
__global__ __launch_bounds__(256,2) void combine(const float* __restrict__ hf,
                                                 const float* __restrict__ hb,
                                                 const float* __restrict__ sup_enc,
                                                 float* __restrict__ semb,
                                                 float* __restrict__ sn){
  int tid=threadIdx.x, l=tid&63, w=tid>>6;
  int m0=blockIdx.x*16;
  #pragma unroll
  for(int q=0;q<4;q++){
    size_t m=(size_t)m0 + w*4 + q;
    float v = hf[m*64+l] + hb[m*64+l] + sup_enc[m*64+l];
    semb[m*64+l]=v;
    float s=v*v;
    #pragma unroll
    for (int o=32;o>0;o>>=1) s += __shfl_xor(s,o,64);
    if (l==0) sn[m]=sqrtf(s);
  }
}

// ------- zx-GEMM prologue + ALL 5 K-iterations + final cosine softmax in ONE kernel -------
// (256,1): ~230 live floats/thread must stay in arch VGPRs -> no spill (R8 lesson).
// zx computed per-block from LDS-staged tgt_enc tile (wih regs die after prologue);
// eliminates the zx HBM round-trip and one 512-block dispatch.
__global__ __launch_bounds__(256,1) void fused_K2(const float* __restrict__ tgt_enc,
                                                  const float* __restrict__ Wih,
                                                  const float* __restrict__ bih,
                                                  const float* __restrict__ bhh,
                                                  const float* __restrict__ Whh,
                                                  const float* __restrict__ semb,
                                                  const float* __restrict__ sn,
                                                  float* __restrict__ out){
  int tid=threadIdx.x, l=tid&63, w=tid>>6;
  int b=blockIdx.x>>3, t0=(blockIdx.x&7)*16;
  int m0=b*Tn+t0;
  int g=tid;                      // gate index AND support-row index j
  bool valid = g<NKn;
  const float* sbase = semb + (size_t)b*NKn*64;
  __shared__ __attribute__((aligned(16))) float hu_s[16*64];   // 4 KB (first: tgt_enc tile)
  __shared__ __attribute__((aligned(16))) float sbuf[16*256];  // z 16 KB / att[200*20]
  __shared__ __attribute__((aligned(16))) float hn_s[16*64];   // h_next 4 KB
  __shared__ float wredA[64], wredB[64];
  // ---- prologue: stage tgt_enc tile; compute zx tile in-block ----
  #pragma unroll
  for(int q=0;q<4;q++){ int r=4*w+q; hu_s[r*64+l]=tgt_enc[(size_t)(m0+r)*64+l]; }
  float zxr[16];
  {
    float wih[64];
    const float4* W4=(const float4*)(Wih+(size_t)g*64);
    #pragma unroll
    for(int q=0;q<16;q++){ float4 v=W4[q]; wih[4*q]=v.x; wih[4*q+1]=v.y; wih[4*q+2]=v.z; wih[4*q+3]=v.w; }
    float bias=bih[g]+bhh[g];
    __syncthreads();                               // tile staged
    #pragma unroll
    for(int r=0;r<16;r++){
      const float4* x4=(const float4*)&hu_s[r*64];
      float a0=bias,a1=0.f,a2=0.f,a3=0.f;
      #pragma unroll
      for(int kc=0;kc<16;kc++){
        float4 h4=x4[kc];
        a0=fmaf(wih[4*kc+0],h4.x,a0);
        a1=fmaf(wih[4*kc+1],h4.y,a1);
        a2=fmaf(wih[4*kc+2],h4.z,a2);
        a3=fmaf(wih[4*kc+3],h4.w,a3);
      }
      zxr[r]=(a0+a1)+(a2+a3);
    }
  }
  float xr[4];
  #pragma unroll
  for(int q=0;q<4;q++) xr[q]=hu_s[(q*4+w)*64+l];   // tgt_enc rows for h_next += x
  // ---- persistent state for the K loop ----
  float wr[64], s4f[64];
  {
    const float4* W4=(const float4*)(Whh+(size_t)g*64);
    #pragma unroll
    for(int q=0;q<16;q++){ float4 v=W4[q]; wr[4*q]=v.x; wr[4*q+1]=v.y; wr[4*q+2]=v.z; wr[4*q+3]=v.w; }
  }
  if(valid){
    const float4* sp=(const float4*)(sbase+(size_t)g*64);
    #pragma unroll
    for(int q=0;q<16;q++){ float4 v=sp[q]; s4f[4*q]=v.x; s4f[4*q+1]=v.y; s4f[4*q+2]=v.z; s4f[4*q+3]=v.w; }
  } else {
    #pragma unroll
    for(int q=0;q<64;q++) s4f[q]=0.f;
  }
  float snr = valid ? sn[(size_t)b*NKn+g] : 1.f;
  float cq[4]={0.f,0.f,0.f,0.f};
  float scr[16], ex[16], mx[16];
  for(int k=0;k<5;k++){
    if(k==0){
      #pragma unroll
      for(int r=0;r<16;r++){ sbuf[r*256+g]=zxr[r]; scr[r]=0.f; }
    } else {
      #pragma unroll
      for(int r=0;r<16;r++){
        float z0=zxr[r], z1=0.f, sc0=0.f, sc1=0.f;
        const float4* h4p=(const float4*)&hu_s[r*64];
        #pragma unroll
        for(int kc=0;kc<16;kc++){
          float4 h4=h4p[kc];
          z0 =fmaf(wr[4*kc+0] ,h4.x,z0 ); sc0=fmaf(s4f[4*kc+0],h4.x,sc0);
          z1 =fmaf(wr[4*kc+1] ,h4.y,z1 ); sc1=fmaf(s4f[4*kc+1],h4.y,sc1);
          z0 =fmaf(wr[4*kc+2] ,h4.z,z0 ); sc0=fmaf(s4f[4*kc+2],h4.z,sc0);
          z1 =fmaf(wr[4*kc+3] ,h4.w,z1 ); sc1=fmaf(s4f[4*kc+3],h4.w,sc1);
        }
        sbuf[r*256+g]=z0+z1;
        scr[r]=sc0+sc1;
      }
    }
    __syncthreads();                               // B1: z ready (hu_s reads done)
    #pragma unroll
    for(int q=0;q<4;q++){
      int r=q*4+w;
      float zi=sbuf[r*256+l], zf=sbuf[r*256+64+l], zg=sbuf[r*256+128+l], zo=sbuf[r*256+192+l];
      float c=sigm_f(zf)*cq[q]+sigm_f(zi)*tanh_f(zg);
      cq[q]=c;
      hn_s[r*64+l]=sigm_f(zo)*tanh_f(c)+xr[q];
    }
    if(k<4){
      #pragma unroll
      for(int t=0;t<16;t++){
        float m = valid ? scr[t] : -1e30f;
        #pragma unroll
        for(int o=32;o>0;o>>=1) m=fmaxf(m,__shfl_xor(m,o,64));
        mx[t]=m;
      }
      if(l==0){
        #pragma unroll
        for(int t=0;t<16;t++) wredA[t*4+w]=mx[t];
      }
      __syncthreads();                             // B2: z reads done; wredA ready
      #pragma unroll
      for(int t=0;t<16;t++){
        const float4 m4=*(const float4*)&wredA[t*4];
        float gm=fmaxf(fmaxf(m4.x,m4.y),fmaxf(m4.z,m4.w));
        float e=valid?__expf(scr[t]-gm):0.f;
        ex[t]=e;
        float s=e;
        #pragma unroll
        for(int o=32;o>0;o>>=1) s+=__shfl_xor(s,o,64);
        mx[t]=s;
      }
      if(l==0){
        #pragma unroll
        for(int t=0;t<16;t++) wredB[t*4+w]=mx[t];
      }
      __syncthreads();                             // B3: wredB ready
      #pragma unroll
      for(int t=0;t<16;t++){
        const float4 s4v=*(const float4*)&wredB[t*4];
        float tot=(s4v.x+s4v.y)+(s4v.z+s4v.w);
        ex[t]*=1.0f/tot;                           // att
      }
      if(valid){
        #pragma unroll
        for(int cg=0;cg<4;cg++)
          *(float4*)&sbuf[g*20+4*cg]=make_float4(ex[4*cg+0],ex[4*cg+1],ex[4*cg+2],ex[4*cg+3]);
      }
      __syncthreads();                             // B4: att + hn_s visible
      float r0=0.f,r1=0.f,r2=0.f,r3=0.f;
      #pragma unroll 8
      for(int j=0;j<NKn;j++){
        float4 a4=*(const float4*)&sbuf[j*20+w*4];
        float sv=sbase[(size_t)j*64+l];            // L2-resident, coalesced (VMEM pipe)
        r0=fmaf(a4.x,sv,r0);
        r1=fmaf(a4.y,sv,r1);
        r2=fmaf(a4.z,sv,r2);
        r3=fmaf(a4.w,sv,r3);
      }
      int rb=w*4;
      hu_s[(rb+0)*64+l]=r0 + hn_s[(rb+0)*64+l];
      hu_s[(rb+1)*64+l]=r1 + hn_s[(rb+1)*64+l];
      hu_s[(rb+2)*64+l]=r2 + hn_s[(rb+2)*64+l];
      hu_s[(rb+3)*64+l]=r3 + hn_s[(rb+3)*64+l];
      __syncthreads();                             // B5: hu ready for next iteration
    }
  }
  __syncthreads();                                 // hn_s complete
  float tnorm[16];
  #pragma unroll
  for(int t=0;t<16;t++){
    float v=hn_s[t*64+l];
    float s=v*v;
    #pragma unroll
    for(int o=32;o>0;o>>=1) s+=__shfl_xor(s,o,64);
    tnorm[t]=sqrtf(s);
  }
  #pragma unroll
  for(int t=0;t<16;t++){
    const float4* h4p=(const float4*)&hn_s[t*64];
    float a0=0.f,a1=0.f;
    #pragma unroll
    for(int kc=0;kc<16;kc++){
      float4 h4=h4p[kc];
      a0=fmaf(s4f[4*kc+0],h4.x,a0);
      a1=fmaf(s4f[4*kc+1],h4.y,a1);
      a0=fmaf(s4f[4*kc+2],h4.z,a0);
      a1=fmaf(s4f[4*kc+3],h4.w,a1);
    }
    scr[t]=(a0+a1) / fmaxf(tnorm[t]*snr,1e-8f);
  }
  #pragma unroll
  for(int t=0;t<16;t++){
    float m = valid ? scr[t] : -1e30f;
    #pragma unroll
    for(int o=32;o>0;o>>=1) m=fmaxf(m,__shfl_xor(m,o,64));
    mx[t]=m;
  }
  if(l==0){
    #pragma unroll
    for(int t=0;t<16;t++) wredA[t*4+w]=mx[t];
  }
  __syncthreads();
  #pragma unroll
  for(int t=0;t<16;t++){
    const float4 m4=*(const float4*)&wredA[t*4];
    float gm=fmaxf(fmaxf(m4.x,m4.y),fmaxf(m4.z,m4.w));
    float e=valid?__expf(scr[t]-gm):0.f;
    ex[t]=e;
    float s=e;
    #pragma unroll
    for(int o=32;o>0;o>>=1) s+=__shfl_xor(s,o,64);
    mx[t]=s;
  }
  if(l==0){
    #pragma unroll
    for(int t=0;t<16;t++) wredB[t*4+w]=mx[t];
  }
  __syncthreads();
  #pragma unroll
  for(int t=0;t<16;t++){
    const float4 s4v=*(const float4*)&wredB[t*4];
    float tot=(s4v.x+s4v.y)+(s4v.z+s4v.w);
    if(valid) out[((size_t)(m0+t))*NKn + g]=ex[t]*(1.0f/tot);
  }
}

extern "C" void kernel_launch(void* const* d_in, const int* in_sizes, int n_in,
                              void* d_out, int out_size, void* d_ws, size_t ws_size,
                              hipStream_t stream) {
  (void)in_sizes; (void)n_in; (void)out_size; (void)ws_size;
  const int*   sup_toks = (const int*)d_in[0];
  const int*   tgt_toks = (const int*)d_in[1];
  const float* emb      = (const float*)d_in[2];
  const float* f_Wih    = (const float*)d_in[3];
  const float* f_Whh    = (const float*)d_in[4];
  const float* f_bih    = (const float*)d_in[5];
  const float* f_bhh    = (const float*)d_in[6];
  const float* gf_Wih   = (const float*)d_in[7];
  const float* gf_Whh   = (const float*)d_in[8];
  const float* gf_bih   = (const float*)d_in[9];
  const float* gf_bhh   = (const float*)d_in[10];
  const float* gb_Wih   = (const float*)d_in[11];
  const float* gb_Whh   = (const float*)d_in[12];
  const float* gb_bih   = (const float*)d_in[13];
  const float* gb_bhh   = (const float*)d_in[14];

  float* ws = (float*)d_ws;
  float* sup_enc = ws;                         // 819200
  float* tgt_enc = sup_enc + 819200;           // 524288
  float* bufA    = tgt_enc + 524288;           // 3276800 : xg_f
  float* bufB    = bufA    + 3276800;          // 3276800 : xg_b
  float* semb    = bufB    + 3276800;          // 819200  : hf, then sup_emb
  float* hb      = semb    + 819200;           // 819200
  float* sn      = hb      + 819200;           // 12800

  float* xg_f = bufA;
  float* xg_b = bufB;

  embed_all<<<1312,256,0,stream>>>(sup_toks, tgt_toks, emb, sup_enc, tgt_enc);
  gemm_sup2<<<800,256,0,stream>>>(sup_enc, gf_Wih, gb_Wih,
                                  gf_bih, gf_bhh, gb_bih, gb_bhh, xg_f, xg_b);
  lstm_seq<<<128,256,0,stream>>>(xg_f, xg_b, gf_Whh, gb_Whh, semb /*hf*/, hb);
  combine<<<800,256,0,stream>>>(semb, hb, sup_enc, semb, sn);
  fused_K2<<<512,256,0,stream>>>(tgt_enc, f_Wih, f_bih, f_bhh, f_Whh,
                                 semb, sn, (float*)d_out);
}

// Round 12
// 351.217 us; speedup vs baseline: 1.8169x; 1.8169x over previous
//
#include <hip/hip_runtime.h>

#define Bn   64
#define Tn   128
#define NKn  200
#define En   64
#define Ln   40

__device__ __forceinline__ float sigm_f(float x){ return 1.0f/(1.0f+__expf(-x)); }
__device__ __forceinline__ float tanh_f(float x){ float e=__expf(2.0f*x); return 1.0f-2.0f/(e+1.0f); }
__device__ __forceinline__ float rdl(float v, int ln){
  return __uint_as_float(__builtin_amdgcn_readlane(__float_as_uint(v), (unsigned)ln));
}

// ---------------- both embedding gather-sums in one grid ----------------
__global__ __launch_bounds__(256) void embed_all(const int* __restrict__ sup,
                                                 const int* __restrict__ tgt,
                                                 const float* __restrict__ emb,
                                                 float* __restrict__ sup_enc,
                                                 float* __restrict__ tgt_enc){
  int tid = threadIdx.x;
  int gr  = blockIdx.x*16 + (tid>>4);
  int e4  = tid & 15;
  const int* tr; float* out;
  if (gr < 12800){ tr = sup + (size_t)gr*Ln;        out = sup_enc + (size_t)gr*64; }
  else           { int r2=gr-12800; tr = tgt + (size_t)r2*Ln; out = tgt_enc + (size_t)r2*64; }
  float4 acc = {0.f,0.f,0.f,0.f};
  #pragma unroll 4
  for (int t=0;t<Ln;t++){
    int tok = tr[t];
    float4 v = ((const float4*)emb)[(size_t)tok*16 + e4];
    acc.x+=v.x; acc.y+=v.y; acc.z+=v.z; acc.w+=v.w;
  }
  ((float4*)out)[e4] = acc;
}

// ------- both support GEMMs in ONE pass: thread holds Wa row g AND Wb row g --------
__global__ __launch_bounds__(256,1) void gemm_sup2(const float* __restrict__ x,
                                                   const float* __restrict__ Wa, const float* __restrict__ Wb,
                                                   const float* __restrict__ ba1,const float* __restrict__ ba2,
                                                   const float* __restrict__ bb1,const float* __restrict__ bb2,
                                                   float* __restrict__ outa, float* __restrict__ outb){
  int tid=threadIdx.x, l=tid&63, w=tid>>6;
  int g=tid;
  int m0 = blockIdx.x*16;
  __shared__ __attribute__((aligned(16))) float xs[16*64];
  #pragma unroll
  for(int q=0;q<4;q++){ int r=4*w+q; xs[r*64+l]=x[(size_t)(m0+r)*64+l]; }
  float wa[64], wb[64];
  {
    const float4* A4=(const float4*)(Wa + (size_t)g*64);
    const float4* B4=(const float4*)(Wb + (size_t)g*64);
    #pragma unroll
    for(int q=0;q<16;q++){
      float4 va=A4[q]; wa[4*q]=va.x; wa[4*q+1]=va.y; wa[4*q+2]=va.z; wa[4*q+3]=va.w;
      float4 vb=B4[q]; wb[4*q]=vb.x; wb[4*q+1]=vb.y; wb[4*q+2]=vb.z; wb[4*q+3]=vb.w;
    }
  }
  float biasa=ba1[g]+ba2[g], biasb=bb1[g]+bb2[g];
  __syncthreads();
  #pragma unroll
  for(int r=0;r<16;r++){
    const float4* x4=(const float4*)&xs[r*64];
    float a0=biasa,a1=0.f,b0=biasb,b1=0.f;
    #pragma unroll
    for(int kc=0;kc<16;kc++){
      float4 h4=x4[kc];
      a0=fmaf(wa[4*kc+0],h4.x,a0); b0=fmaf(wb[4*kc+0],h4.x,b0);
      a1=fmaf(wa[4*kc+1],h4.y,a1); b1=fmaf(wb[4*kc+1],h4.y,b1);
      a0=fmaf(wa[4*kc+2],h4.z,a0); b0=fmaf(wb[4*kc+2],h4.z,b0);
      a1=fmaf(wa[4*kc+3],h4.w,a1); b1=fmaf(wb[4*kc+3],h4.w,b1);
    }
    outa[(size_t)(m0+r)*256+g]=a0+a1;
    outb[(size_t)(m0+r)*256+g]=b0+b1;
  }
}

// ---------------- BiLSTM: R2-exact structure (best measured: 113 us) ----------------
__global__ __launch_bounds__(256,1) void lstm_seq(const float* __restrict__ xg_f,
                                                  const float* __restrict__ xg_b,
                                                  const float* __restrict__ Whh_f,
                                                  const float* __restrict__ Whh_b,
                                                  float* __restrict__ hf,
                                                  float* __restrict__ hb){
  int tid=threadIdx.x, l=tid&63, w=tid>>6;
  int dir=blockIdx.x>>6, b=blockIdx.x&63;
  const float* xg = dir? xg_b : xg_f;
  const float* Whh= dir? Whh_b: Whh_f;
  float* out = dir? hb : hf;
  float wr[64];
  const float4* W4=(const float4*)(Whh+(size_t)(w*64+l)*64);
  #pragma unroll
  for(int q=0;q<16;q++){ float4 v=W4[q]; wr[4*q]=v.x; wr[4*q+1]=v.y; wr[4*q+2]=v.z; wr[4*q+3]=v.w; }
  __shared__ float z_s[2][256];
  float h=0.f, c=0.f;
  const int tstart = dir?(NKn-1):0, dt = dir?-1:1;
  const float* xgb = xg + (size_t)b*NKn*256 + w*64 + l;
  float xv = xgb[(size_t)tstart*256];
  for(int s=0;s<NKn;s++){
    int t=tstart+s*dt;
    float xnx=0.f;
    if (s<NKn-1) xnx = xgb[(size_t)(t+dt)*256];     // prefetch next step's xg
    float a0=xv,a1=0.f,a2=0.f,a3=0.f;
    #pragma unroll
    for(int q=0;q<16;q++){
      a0=fmaf(wr[4*q+0],rdl(h,4*q+0),a0);
      a1=fmaf(wr[4*q+1],rdl(h,4*q+1),a1);
      a2=fmaf(wr[4*q+2],rdl(h,4*q+2),a2);
      a3=fmaf(wr[4*q+3],rdl(h,4*q+3),a3);
    }
    z_s[s&1][tid]=(a0+a1)+(a2+a3);
    __syncthreads();                                 // double-buffered z -> only barrier
    float zi=z_s[s&1][l], zf=z_s[s&1][64+l], zg=z_s[s&1][128+l], zo=z_s[s&1][192+l];
    c = sigm_f(zf)*c + sigm_f(zi)*tanh_f(zg);        // redundant per wave, h stays in regs
    h = sigm_f(zo)*tanh_f(c);
    if(w==0) out[((size_t)b*NKn+t)*64+l]=h;
    xv=xnx;
  }
}

// ---------------- zx GEMM (blocks 0..511) + combine/norms (blocks 512..1311) --------------
__global__ __launch_bounds__(256,2) void gemmz_combine(const float* __restrict__ tgt_enc,
                                                       const float* __restrict__ W,
                                                       const float* __restrict__ b1,
                                                       const float* __restrict__ b2,
                                                       float* __restrict__ zx,
                                                       const float* __restrict__ hf,
                                                       const float* __restrict__ hb,
                                                       const float* __restrict__ sup_enc,
                                                       float* __restrict__ semb,
                                                       float* __restrict__ sn){
  int tid=threadIdx.x, l=tid&63, w=tid>>6;
  int blk=blockIdx.x;
  if (blk < 512){
    int g=tid, m0=blk*16;
    __shared__ __attribute__((aligned(16))) float xs[16*64];
    #pragma unroll
    for(int q=0;q<4;q++){ int r=4*w+q; xs[r*64+l]=tgt_enc[(size_t)(m0+r)*64+l]; }
    float wr[64];
    const float4* W4=(const float4*)(W + (size_t)g*64);
    #pragma unroll
    for(int q=0;q<16;q++){ float4 v=W4[q]; wr[4*q]=v.x; wr[4*q+1]=v.y; wr[4*q+2]=v.z; wr[4*q+3]=v.w; }
    float bias=b1[g]+b2[g];
    __syncthreads();
    #pragma unroll
    for(int r=0;r<16;r++){
      const float4* x4=(const float4*)&xs[r*64];
      float a0=bias,a1=0.f,a2=0.f,a3=0.f;
      #pragma unroll
      for(int kc=0;kc<16;kc++){
        float4 h4=x4[kc];
        a0=fmaf(wr[4*kc+0],h4.x,a0);
        a1=fmaf(wr[4*kc+1],h4.y,a1);
        a2=fmaf(wr[4*kc+2],h4.z,a2);
        a3=fmaf(wr[4*kc+3],h4.w,a3);
      }
      zx[(size_t)(m0+r)*256+g]=(a0+a1)+(a2+a3);
    }
  } else {
    int m0=(blk-512)*16;
    #pragma unroll
    for(int q=0;q<4;q++){
      size_t m=(size_t)m0 + w*4 + q;
      float v = hf[m*64+l] + hb[m*64+l] + sup_enc[m*64+l];
      semb[m*64+l]=v;
      float s=v*v;
      #pragma unroll
      for (int o=32;o>0;o>>=1) s += __shfl_xor(s,o,64);
      if (l==0) sn[m]=sqrtf(s);
    }
  }
}

// ------- ALL 5 K-iterations + final cosine softmax in ONE kernel (row-local K loop) -------
// (256,1): ~200 live floats/thread must stay in arch VGPRs -> no spill (R8/R11 lesson:
// do NOT add a zx prologue; zx comes from global).
__global__ __launch_bounds__(256,1) void fused_K(const float* __restrict__ zx,
                                                 const float* __restrict__ Whh,
                                                 const float* __restrict__ x,
                                                 const float* __restrict__ semb,
                                                 const float* __restrict__ sn,
                                                 float* __restrict__ out){
  int tid=threadIdx.x, l=tid&63, w=tid>>6;
  int b=blockIdx.x>>3, t0=(blockIdx.x&7)*16;
  int m0=b*Tn+t0;
  int g=tid;                      // gate index AND support-row index j
  bool valid = g<NKn;
  const float* sbase = semb + (size_t)b*NKn*64;
  __shared__ __attribute__((aligned(16))) float hu_s[16*64];   // 4 KB
  __shared__ __attribute__((aligned(16))) float sbuf[16*256];  // z 16 KB / att[200*20]
  __shared__ __attribute__((aligned(16))) float hn_s[16*64];   // h_next 4 KB
  __shared__ float wredA[64], wredB[64];
  float wr[64], s4f[64];
  {
    const float4* W4=(const float4*)(Whh+(size_t)g*64);
    #pragma unroll
    for(int q=0;q<16;q++){ float4 v=W4[q]; wr[4*q]=v.x; wr[4*q+1]=v.y; wr[4*q+2]=v.z; wr[4*q+3]=v.w; }
  }
  if(valid){
    const float4* sp=(const float4*)(sbase+(size_t)g*64);
    #pragma unroll
    for(int q=0;q<16;q++){ float4 v=sp[q]; s4f[4*q]=v.x; s4f[4*q+1]=v.y; s4f[4*q+2]=v.z; s4f[4*q+3]=v.w; }
  } else {
    #pragma unroll
    for(int q=0;q<64;q++) s4f[q]=0.f;
  }
  float zxr[16];
  #pragma unroll
  for(int r=0;r<16;r++) zxr[r]=zx[(size_t)(m0+r)*256+g];
  float xr[4];
  #pragma unroll
  for(int q=0;q<4;q++) xr[q]=x[(size_t)(m0+q*4+w)*64+l];
  float snr = valid ? sn[(size_t)b*NKn+g] : 1.f;
  float cq[4]={0.f,0.f,0.f,0.f};
  float scr[16], ex[16], mx[16];
  for(int k=0;k<5;k++){
    if(k==0){
      #pragma unroll
      for(int r=0;r<16;r++){ sbuf[r*256+g]=zxr[r]; scr[r]=0.f; }
    } else {
      #pragma unroll
      for(int r=0;r<16;r++){
        float z0=zxr[r], z1=0.f, sc0=0.f, sc1=0.f;
        const float4* h4p=(const float4*)&hu_s[r*64];
        #pragma unroll
        for(int kc=0;kc<16;kc++){
          float4 h4=h4p[kc];
          z0 =fmaf(wr[4*kc+0] ,h4.x,z0 ); sc0=fmaf(s4f[4*kc+0],h4.x,sc0);
          z1 =fmaf(wr[4*kc+1] ,h4.y,z1 ); sc1=fmaf(s4f[4*kc+1],h4.y,sc1);
          z0 =fmaf(wr[4*kc+2] ,h4.z,z0 ); sc0=fmaf(s4f[4*kc+2],h4.z,sc0);
          z1 =fmaf(wr[4*kc+3] ,h4.w,z1 ); sc1=fmaf(s4f[4*kc+3],h4.w,sc1);
        }
        sbuf[r*256+g]=z0+z1;
        scr[r]=sc0+sc1;
      }
    }
    __syncthreads();                               // B1: z ready (hu_s reads done)
    #pragma unroll
    for(int q=0;q<4;q++){
      int r=q*4+w;
      float zi=sbuf[r*256+l], zf=sbuf[r*256+64+l], zg=sbuf[r*256+128+l], zo=sbuf[r*256+192+l];
      float c=sigm_f(zf)*cq[q]+sigm_f(zi)*tanh_f(zg);
      cq[q]=c;
      hn_s[r*64+l]=sigm_f(zo)*tanh_f(c)+xr[q];
    }
    if(k<4){
      #pragma unroll
      for(int t=0;t<16;t++){
        float m = valid ? scr[t] : -1e30f;
        #pragma unroll
        for(int o=32;o>0;o>>=1) m=fmaxf(m,__shfl_xor(m,o,64));
        mx[t]=m;
      }
      if(l==0){
        #pragma unroll
        for(int t=0;t<16;t++) wredA[t*4+w]=mx[t];
      }
      __syncthreads();                             // B2: z reads done; wredA ready
      #pragma unroll
      for(int t=0;t<16;t++){
        const float4 m4=*(const float4*)&wredA[t*4];
        float gm=fmaxf(fmaxf(m4.x,m4.y),fmaxf(m4.z,m4.w));
        float e=valid?__expf(scr[t]-gm):0.f;
        ex[t]=e;
        float s=e;
        #pragma unroll
        for(int o=32;o>0;o>>=1) s+=__shfl_xor(s,o,64);
        mx[t]=s;
      }
      if(l==0){
        #pragma unroll
        for(int t=0;t<16;t++) wredB[t*4+w]=mx[t];
      }
      __syncthreads();                             // B3: wredB ready
      #pragma unroll
      for(int t=0;t<16;t++){
        const float4 s4v=*(const float4*)&wredB[t*4];
        float tot=(s4v.x+s4v.y)+(s4v.z+s4v.w);
        ex[t]*=1.0f/tot;                           // att
      }
      if(valid){
        #pragma unroll
        for(int cg=0;cg<4;cg++)
          *(float4*)&sbuf[g*20+4*cg]=make_float4(ex[4*cg+0],ex[4*cg+1],ex[4*cg+2],ex[4*cg+3]);
      }
      __syncthreads();                             // B4: att + hn_s visible
      float r0=0.f,r1=0.f,r2=0.f,r3=0.f;
      #pragma unroll 8
      for(int j=0;j<NKn;j++){
        float4 a4=*(const float4*)&sbuf[j*20+w*4];
        float sv=sbase[(size_t)j*64+l];            // L2-resident, coalesced (VMEM pipe)
        r0=fmaf(a4.x,sv,r0);
        r1=fmaf(a4.y,sv,r1);
        r2=fmaf(a4.z,sv,r2);
        r3=fmaf(a4.w,sv,r3);
      }
      int rb=w*4;
      hu_s[(rb+0)*64+l]=r0 + hn_s[(rb+0)*64+l];
      hu_s[(rb+1)*64+l]=r1 + hn_s[(rb+1)*64+l];
      hu_s[(rb+2)*64+l]=r2 + hn_s[(rb+2)*64+l];
      hu_s[(rb+3)*64+l]=r3 + hn_s[(rb+3)*64+l];
      __syncthreads();                             // B5: hu ready for next iteration
    }
  }
  __syncthreads();                                 // hn_s complete
  float tnorm[16];
  #pragma unroll
  for(int t=0;t<16;t++){
    float v=hn_s[t*64+l];
    float s=v*v;
    #pragma unroll
    for(int o=32;o>0;o>>=1) s+=__shfl_xor(s,o,64);
    tnorm[t]=sqrtf(s);
  }
  #pragma unroll
  for(int t=0;t<16;t++){
    const float4* h4p=(const float4*)&hn_s[t*64];
    float a0=0.f,a1=0.f;
    #pragma unroll
    for(int kc=0;kc<16;kc++){
      float4 h4=h4p[kc];
      a0=fmaf(s4f[4*kc+0],h4.x,a0);
      a1=fmaf(s4f[4*kc+1],h4.y,a1);
      a0=fmaf(s4f[4*kc+2],h4.z,a0);
      a1=fmaf(s4f[4*kc+3],h4.w,a1);
    }
    scr[t]=(a0+a1) / fmaxf(tnorm[t]*snr,1e-8f);
  }
  #pragma unroll
  for(int t=0;t<16;t++){
    float m = valid ? scr[t] : -1e30f;
    #pragma unroll
    for(int o=32;o>0;o>>=1) m=fmaxf(m,__shfl_xor(m,o,64));
    mx[t]=m;
  }
  if(l==0){
    #pragma unroll
    for(int t=0;t<16;t++) wredA[t*4+w]=mx[t];
  }
  __syncthreads();
  #pragma unroll
  for(int t=0;t<16;t++){
    const float4 m4=*(const float4*)&wredA[t*4];
    float gm=fmaxf(fmaxf(m4.x,m4.y),fmaxf(m4.z,m4.w));
    float e=valid?__expf(scr[t]-gm):0.f;
    ex[t]=e;
    float s=e;
    #pragma unroll
    for(int o=32;o>0;o>>=1) s+=__shfl_xor(s,o,64);
    mx[t]=s;
  }
  if(l==0){
    #pragma unroll
    for(int t=0;t<16;t++) wredB[t*4+w]=mx[t];
  }
  __syncthreads();
  #pragma unroll
  for(int t=0;t<16;t++){
    const float4 s4v=*(const float4*)&wredB[t*4];
    float tot=(s4v.x+s4v.y)+(s4v.z+s4v.w);
    if(valid) out[((size_t)(m0+t))*NKn + g]=ex[t]*(1.0f/tot);
  }
}

extern "C" void kernel_launch(void* const* d_in, const int* in_sizes, int n_in,
                              void* d_out, int out_size, void* d_ws, size_t ws_size,
                              hipStream_t stream) {
  (void)in_sizes; (void)n_in; (void)out_size; (void)ws_size;
  const int*   sup_toks = (const int*)d_in[0];
  const int*   tgt_toks = (const int*)d_in[1];
  const float* emb      = (const float*)d_in[2];
  const float* f_Wih    = (const float*)d_in[3];
  const float* f_Whh    = (const float*)d_in[4];
  const float* f_bih    = (const float*)d_in[5];
  const float* f_bhh    = (const float*)d_in[6];
  const float* gf_Wih   = (const float*)d_in[7];
  const float* gf_Whh   = (const float*)d_in[8];
  const float* gf_bih   = (const float*)d_in[9];
  const float* gf_bhh   = (const float*)d_in[10];
  const float* gb_Wih   = (const float*)d_in[11];
  const float* gb_Whh   = (const float*)d_in[12];
  const float* gb_bih   = (const float*)d_in[13];
  const float* gb_bhh   = (const float*)d_in[14];

  float* ws = (float*)d_ws;
  float* sup_enc = ws;                         // 819200
  float* tgt_enc = sup_enc + 819200;           // 524288
  float* bufA    = tgt_enc + 524288;           // 3276800 : xg_f, later zx
  float* bufB    = bufA    + 3276800;          // 3276800 : xg_b
  float* semb    = bufB    + 3276800;          // 819200  : hf, then sup_emb
  float* hb      = semb    + 819200;           // 819200
  float* sn      = hb      + 819200;           // 12800

  float* xg_f = bufA;
  float* xg_b = bufB;

  embed_all<<<1312,256,0,stream>>>(sup_toks, tgt_toks, emb, sup_enc, tgt_enc);
  gemm_sup2<<<800,256,0,stream>>>(sup_enc, gf_Wih, gb_Wih,
                                  gf_bih, gf_bhh, gb_bih, gb_bhh, xg_f, xg_b);
  lstm_seq<<<128,256,0,stream>>>(xg_f, xg_b, gf_Whh, gb_Whh, semb /*hf*/, hb);

  float* zx = bufA;                    // xg_f dead after lstm

  gemmz_combine<<<1312,256,0,stream>>>(tgt_enc, f_Wih, f_bih, f_bhh, zx,
                                       semb, hb, sup_enc, semb, sn);

  fused_K<<<512,256,0,stream>>>(zx, f_Whh, tgt_enc, semb, sn, (float*)d_out);
}